// Round 4
// baseline (8089.157 us; speedup 1.0000x reference)
//
#include <hip/hip_runtime.h>
#include <math.h>

#define NN 20000      // nodes
#define NE 320000     // edges
#define BB 2
#define TT 24
#define FI 32
#define HH 128

// ---------------- edge_index dtype detection ----------------
// If edge_index is int64 (little-endian, values < 2^31), every odd int32
// word is a zero high-word. If int32, odd words are random src indices.
__global__ void k_detect(const int* __restrict__ ei, int* __restrict__ flag) {
    int t = threadIdx.x;  // 64 threads
    int nz = 0;
    for (int i = 0; i < 4; ++i) nz |= (ei[2 * (t + 64 * i) + 1] != 0);
    unsigned long long m = __ballot(nz);
    if (t == 0) flag[0] = (m != 0ull) ? 0 : 1;   // 1 => int64
}

__device__ __forceinline__ int eidx(const int* __restrict__ ei, int i, int f64) {
    return f64 ? ei[2 * i] : ei[i];
}

// ---------------- graph preprocessing ----------------

__global__ void k_deg_count(const int* __restrict__ ei, const float* __restrict__ w,
                            float* __restrict__ deg, int* __restrict__ counts,
                            const int* __restrict__ flag) {
    int e = blockIdx.x * blockDim.x + threadIdx.x;
    if (e >= NE) return;
    int f64 = flag[0];
    int s = eidx(ei, e, f64);
    int d = eidx(ei, NE + e, f64);
    atomicAdd(&deg[s], w[e]);
    atomicAdd(&counts[d], 1);
}

__global__ void k_dinv(const float* __restrict__ deg, float* __restrict__ dinv) {
    int n = blockIdx.x * blockDim.x + threadIdx.x;
    if (n >= NN) return;
    float d = deg[n];
    dinv[n] = d > 0.f ? rsqrtf(d) : 0.f;
}

__global__ void k_norm(const int* __restrict__ ei, const float* __restrict__ w,
                       const float* __restrict__ dinv, float* __restrict__ normv,
                       const int* __restrict__ flag) {
    int e = blockIdx.x * blockDim.x + threadIdx.x;
    if (e >= NE) return;
    int f64 = flag[0];
    normv[e] = -dinv[eidx(ei, e, f64)] * w[e] * dinv[eidx(ei, NE + e, f64)];
}

// single-block exclusive scan of counts[NN] -> rowptr[NN+1]
__global__ void k_scan(const int* __restrict__ counts, int* __restrict__ rowptr) {
    __shared__ int sums[1024];
    int t = threadIdx.x;
    const int CH = (NN + 1023) / 1024;
    int start = t * CH;
    int s = 0;
    for (int i = 0; i < CH; ++i) {
        int idx = start + i;
        if (idx < NN) s += counts[idx];
    }
    sums[t] = s;
    __syncthreads();
    for (int off = 1; off < 1024; off *= 2) {
        int v = (t >= off) ? sums[t - off] : 0;
        __syncthreads();
        sums[t] += v;
        __syncthreads();
    }
    int run = (t > 0) ? sums[t - 1] : 0;
    for (int i = 0; i < CH; ++i) {
        int idx = start + i;
        if (idx < NN) { rowptr[idx] = run; run += counts[idx]; }
    }
    if (t == 1023) rowptr[NN] = sums[1023];
}

__global__ void k_copy_int(const int* __restrict__ src, int* __restrict__ dst, int n) {
    int i = blockIdx.x * blockDim.x + threadIdx.x;
    if (i < n) dst[i] = src[i];
}

__global__ void k_fill(const int* __restrict__ ei, const float* __restrict__ normv,
                       int* __restrict__ cursor, int* __restrict__ col, float* __restrict__ val,
                       const int* __restrict__ flag) {
    int e = blockIdx.x * blockDim.x + threadIdx.x;
    if (e >= NE) return;
    int f64 = flag[0];
    int d = eidx(ei, NE + e, f64);
    int p = atomicAdd(&cursor[d], 1);
    col[p] = eidx(ei, e, f64);
    val[p] = normv[e];
}

// ---------------- SpMM (CSR gather): out = Ltilde @ x ----------------

// C=32, both batches in one 64-thread block per node.
// px layout: [tlocal][b][n][f]; t = t0 + blockIdx.y.
__global__ void k_prop_x(const float* __restrict__ x_seq, int t0,
                         const int* __restrict__ rowptr, const int* __restrict__ col,
                         const float* __restrict__ val, float* __restrict__ px) {
    int n = blockIdx.x;
    int tl = blockIdx.y;
    int t = t0 + tl;
    int f = threadIdx.x & 31;
    int b = threadIdx.x >> 5;
    int beg = rowptr[n], end = rowptr[n + 1];
    const float* xb = x_seq + ((long)(b * TT + t) * NN) * FI;
    float acc = 0.f;
    for (int j = beg; j < end; ++j)
        acc += val[j] * xb[(long)col[j] * FI + f];
    px[(((long)tl * BB + b) * NN + n) * FI + f] = acc;
}

// C=128, grid (NN, BB), 128 threads
__global__ void k_prop_h(const float* __restrict__ hin,
                         const int* __restrict__ rowptr, const int* __restrict__ col,
                         const float* __restrict__ val, float* __restrict__ out) {
    int n = blockIdx.x;
    int b = blockIdx.y;
    int f = threadIdx.x;
    int beg = rowptr[n], end = rowptr[n + 1];
    const float* hb = hin + (long)b * NN * HH;
    float acc = 0.f;
    for (int j = beg; j < end; ++j)
        acc += val[j] * hb[(long)col[j] * HH + f];
    out[((long)b * NN + n) * HH + f] = acc;
}

// ---------------- fused quad-input GEMM ----------------
// v = [A1 | A2 | A3 | A4] @ [Wx ; Wh] + bx + bh   (K = 320, weight N = 128)
// A1 rows addressed as A1 + b*a1_bstride + n*KX1 (row = b*NN + n); A2..A4 contiguous.
// Wx: [KX1+KX2][128] (raw cheb weight [2][din][128]); Wh: [KH1+KH2][128].
// Block computes a 64-row x 64-col slice. 128 threads, 8x4 micro-tile
// (rows {ty*4+i, 32+ty*4+i}, cols tx*4+j). Register-staged pipeline over BK=16.
// EPI 1: grid.y in 0..3: gate = y>>1 (0=z w/ W*z, 1=r w/ W*r), colblk = y&1.
//        s = sigmoid(v); gate 0 -> out0 = s (z); gate 1 -> out1 = s * hcur (h*r)
// EPI 2: grid.y in 0..1: colblk = y. ht = tanh(v); out0 = zin*hcur + (1-zin)*ht
template<int KX1, int KX2, int KH1, int KH2, int EPI>
__global__ __launch_bounds__(128)
void k_gemm(const float* __restrict__ A1, long a1_bstride,
            const float* __restrict__ A2,
            const float* __restrict__ A3,
            const float* __restrict__ A4,
            const float* __restrict__ Wx0, const float* __restrict__ Wh0,
            const float* __restrict__ bx0, const float* __restrict__ bh0,
            const float* __restrict__ Wx1, const float* __restrict__ Wh1,
            const float* __restrict__ bx1, const float* __restrict__ bh1,
            const float* __restrict__ hcur,
            const float* __restrict__ zin,
            float* __restrict__ out0,
            float* __restrict__ out1) {
    constexpr int BM = 64, BN = 64, BK = 16, NW = 128;  // NW = weight row stride
    constexpr int C1 = KX1, C2 = KX1 + KX2, C3 = C2 + KH1, KT = C3 + KH2;
    constexpr int NCH = KT / BK;
    static_assert(NCH * BK == KT, "K must be a multiple of BK");
    __shared__ float As[BK][BM + 4];   // transposed A tile
    __shared__ float Ws[BK][BN];
    const int tid = threadIdx.x;
    const int tx = tid & 15, ty = tid >> 4;          // ty 0..7
    const int row0 = blockIdx.x * BM;
    const int gate   = (EPI == 1) ? (int)(blockIdx.y >> 1) : 0;
    const int colblk = (EPI == 1) ? (int)(blockIdx.y & 1) : (int)blockIdx.y;
    const int col0 = colblk * BN;

    const float* Wx = Wx0; const float* Wh = Wh0;
    const float* bx = bx0; const float* bh = bh0;
    if (EPI == 1 && gate) { Wx = Wx1; Wh = Wh1; bx = bx1; bh = bh1; }

    // A staging map: thread -> (local row rA, k-quad kqA); 8 floats = 2 float4
    const int rA  = tid >> 1;            // 0..63
    const int kqA = (tid & 1) * 8;       // 0 or 8
    const int rowg = row0 + rA;
    const int b = rowg / NN;
    const int n = rowg - b * NN;
    const long offA1 = (long)b * a1_bstride + (long)n * KX1 + kqA;
    const long offA2 = (long)rowg * KX2 + kqA;
    const long offA3 = (long)rowg * KH1 + kqA;
    const long offA4 = (long)rowg * KH2 + kqA;
    // W staging map: rows kWr and kWr+8, cols cW..cW+3
    const int kWr = ty;                  // 0..7
    const int cW  = tx * 4;

    float4 aS0, aS1, wS0, wS1;
    auto LOADA = [&](int ch) {
        const int kbase = ch * BK;
        const float* s;
        if (kbase < C1)      s = A1 + offA1 + kbase;
        else if (kbase < C2) s = A2 + offA2 + (kbase - C1);
        else if (kbase < C3) s = A3 + offA3 + (kbase - C2);
        else                 s = A4 + offA4 + (kbase - C3);
        aS0 = *(const float4*)s;
        aS1 = *(const float4*)(s + 4);
    };
    auto LOADW = [&](int ch) {
        const int kbase = ch * BK;
        const int kg0 = kbase + kWr, kg1 = kbase + kWr + 8;
        const float* s0 = (kg0 < C2) ? (Wx + (long)kg0 * NW) : (Wh + (long)(kg0 - C2) * NW);
        const float* s1 = (kg1 < C2) ? (Wx + (long)kg1 * NW) : (Wh + (long)(kg1 - C2) * NW);
        wS0 = *(const float4*)(s0 + col0 + cW);
        wS1 = *(const float4*)(s1 + col0 + cW);
    };

    float acc[8][4];
#pragma unroll
    for (int i = 0; i < 8; ++i)
#pragma unroll
        for (int j = 0; j < 4; ++j) acc[i][j] = 0.f;

    LOADA(0); LOADW(0);
    for (int ch = 0; ch < NCH; ++ch) {
        __syncthreads();               // previous compute done reading LDS
        As[kqA + 0][rA] = aS0.x;
        As[kqA + 1][rA] = aS0.y;
        As[kqA + 2][rA] = aS0.z;
        As[kqA + 3][rA] = aS0.w;
        As[kqA + 4][rA] = aS1.x;
        As[kqA + 5][rA] = aS1.y;
        As[kqA + 6][rA] = aS1.z;
        As[kqA + 7][rA] = aS1.w;
        *(float4*)&Ws[kWr][cW]     = wS0;
        *(float4*)&Ws[kWr + 8][cW] = wS1;
        __syncthreads();               // tile ready
        if (ch + 1 < NCH) { LOADA(ch + 1); LOADW(ch + 1); }  // overlap w/ compute
#pragma unroll
        for (int kk = 0; kk < BK; ++kk) {
            float4 a0 = *(const float4*)&As[kk][ty << 2];
            float4 a1 = *(const float4*)&As[kk][32 + (ty << 2)];
            float4 w  = *(const float4*)&Ws[kk][tx << 2];
            float a_[8] = {a0.x, a0.y, a0.z, a0.w, a1.x, a1.y, a1.z, a1.w};
            float w_[4] = {w.x, w.y, w.z, w.w};
#pragma unroll
            for (int i = 0; i < 8; ++i)
#pragma unroll
                for (int j = 0; j < 4; ++j)
                    acc[i][j] += a_[i] * w_[j];
        }
    }

    // epilogue: 8 rows x 4 consecutive cols (float4)
    const int cg = col0 + (tx << 2);   // global col of element 0
    float4 bsum;
    bsum.x = bx[cg + 0] + bh[cg + 0];
    bsum.y = bx[cg + 1] + bh[cg + 1];
    bsum.z = bx[cg + 2] + bh[cg + 2];
    bsum.w = bx[cg + 3] + bh[cg + 3];
#pragma unroll
    for (int i = 0; i < 8; ++i) {
        const int row = row0 + ((i < 4) ? ((ty << 2) + i) : (32 + (ty << 2) + (i - 4)));
        const long o = (long)row * 128 + cg;
        float4 v;
        v.x = acc[i][0] + bsum.x;
        v.y = acc[i][1] + bsum.y;
        v.z = acc[i][2] + bsum.z;
        v.w = acc[i][3] + bsum.w;
        if (EPI == 1) {
            float4 s;
            s.x = 1.f / (1.f + expf(-v.x));
            s.y = 1.f / (1.f + expf(-v.y));
            s.z = 1.f / (1.f + expf(-v.z));
            s.w = 1.f / (1.f + expf(-v.w));
            if (gate == 0) {
                *(float4*)&out0[o] = s;                     // z
            } else {
                float4 hc = *(const float4*)&hcur[o];
                s.x *= hc.x; s.y *= hc.y; s.z *= hc.z; s.w *= hc.w;
                *(float4*)&out1[o] = s;                     // h*r
            }
        } else {
            float4 hc = *(const float4*)&hcur[o];
            float4 z  = *(const float4*)&zin[o];
            float4 r;
            r.x = z.x * hc.x + (1.f - z.x) * tanhf(v.x);
            r.y = z.y * hc.y + (1.f - z.y) * tanhf(v.y);
            r.z = z.z * hc.z + (1.f - z.z) * tanhf(v.z);
            r.w = z.w * hc.w + (1.f - z.w) * tanhf(v.w);
            *(float4*)&out0[o] = r;                         // new h (in place)
        }
    }
}

// ---------------- output head ----------------
__global__ void k_out(const float* __restrict__ h, const float* __restrict__ Wl,
                      const float* __restrict__ bl, float* __restrict__ out) {
    int row = blockIdx.x;        // 0 .. B*NN-1
    int lane = threadIdx.x;      // 64
    const float* hr = h + (long)row * HH;
    float a = fmaxf(hr[lane], 0.f) * Wl[lane] + fmaxf(hr[64 + lane], 0.f) * Wl[64 + lane];
#pragma unroll
    for (int off = 32; off > 0; off >>= 1) a += __shfl_down(a, off);
    if (lane == 0) out[row] = a + bl[0];
}

// ---------------- launcher ----------------
extern "C" void kernel_launch(void* const* d_in, const int* in_sizes, int n_in,
                              void* d_out, int out_size, void* d_ws, size_t ws_size,
                              hipStream_t stream) {
    const float* x_seq = (const float*)d_in[0];
    const int*   ei    = (const int*)d_in[1];
    const float* ew    = (const float*)d_in[2];
    const float* Wxz = (const float*)d_in[3],  *bxz = (const float*)d_in[4];
    const float* Whz = (const float*)d_in[5],  *bhz = (const float*)d_in[6];
    const float* Wxr = (const float*)d_in[7],  *bxr = (const float*)d_in[8];
    const float* Whr = (const float*)d_in[9],  *bhr = (const float*)d_in[10];
    const float* Wxh = (const float*)d_in[11], *bxh = (const float*)d_in[12];
    const float* Whh = (const float*)d_in[13], *bhh = (const float*)d_in[14];
    const float* Wl  = (const float*)d_in[15], *bl  = (const float*)d_in[16];
    float* out = (float*)d_out;

    char* p = (char*)d_ws;
    auto alloc = [&](size_t bytes) -> char* {
        char* r = p;
        p += (bytes + 255) & ~(size_t)255;
        return r;
    };
    const long RB = (long)BB * NN;  // 40000 rows

    int*   dflag  = (int*)alloc(4);
    float* deg    = (float*)alloc(NN * 4);
    float* dinv   = (float*)alloc(NN * 4);
    float* normv  = (float*)alloc(NE * 4);
    int*   counts = (int*)alloc(NN * 4);
    int*   rowptr = (int*)alloc((NN + 1) * 4);
    int*   cursor = (int*)alloc(NN * 4);
    int*   ccol   = (int*)alloc(NE * 4);
    float* cval   = (float*)alloc(NE * 4);
    float* hbuf   = (float*)alloc(RB * HH * 4);
    float* ph     = (float*)alloc(RB * HH * 4);   // Ltilde@h, reused as Ltilde@(h*r)
    float* zbuf   = (float*)alloc(RB * HH * 4);
    float* hrbuf  = (float*)alloc(RB * HH * 4);

    // px last: batched over all T if workspace allows (decision constant per ws_size)
    size_t used = (size_t)(p - (char*)d_ws);
    bool batched = (ws_size > used) && ((ws_size - used) >= (size_t)TT * RB * FI * 4 + 256);
    float* px = (float*)alloc(batched ? (size_t)TT * RB * FI * 4 : (size_t)RB * FI * 4);

    // graph preprocessing
    hipMemsetAsync(deg, 0, NN * 4, stream);
    hipMemsetAsync(counts, 0, NN * 4, stream);
    k_detect<<<1, 64, 0, stream>>>(ei, dflag);
    k_deg_count<<<(NE + 255) / 256, 256, 0, stream>>>(ei, ew, deg, counts, dflag);
    k_dinv<<<(NN + 255) / 256, 256, 0, stream>>>(deg, dinv);
    k_norm<<<(NE + 255) / 256, 256, 0, stream>>>(ei, ew, dinv, normv, dflag);
    k_scan<<<1, 1024, 0, stream>>>(counts, rowptr);
    k_copy_int<<<(NN + 255) / 256, 256, 0, stream>>>(rowptr, cursor, NN);
    k_fill<<<(NE + 255) / 256, 256, 0, stream>>>(ei, normv, cursor, ccol, cval, dflag);

    // h0 = 0
    hipMemsetAsync(hbuf, 0, RB * HH * 4, stream);

    if (batched)
        k_prop_x<<<dim3(NN, TT), 64, 0, stream>>>(x_seq, 0, rowptr, ccol, cval, px);

    const long xbstride = (long)TT * NN * FI;
    dim3 gZR(625, 4), gH(625, 2);
    for (int t = 0; t < TT; ++t) {
        const float* xt  = x_seq + (long)t * NN * FI;
        const float* pxt = batched ? (px + (long)t * RB * FI) : px;
        if (!batched)
            k_prop_x<<<dim3(NN, 1), 64, 0, stream>>>(x_seq, t, rowptr, ccol, cval, px);

        // ph = Ltilde @ h
        k_prop_h<<<dim3(NN, BB), HH, 0, stream>>>(hbuf, rowptr, ccol, cval, ph);
        // z = sigmoid([x|px|h|ph]@Wz+bz) (gate 0); hr = sigmoid(...Wr...)*h (gate 1)
        k_gemm<FI, FI, HH, HH, 1><<<gZR, 128, 0, stream>>>(
            xt, xbstride, pxt, hbuf, ph,
            Wxz, Whz, bxz, bhz, Wxr, Whr, bxr, bhr,
            hbuf, nullptr, zbuf, hrbuf);
        // ph = Ltilde @ (h*r)
        k_prop_h<<<dim3(NN, BB), HH, 0, stream>>>(hrbuf, rowptr, ccol, cval, ph);
        // ht = tanh([x|px|hr|phr] @ Wh + bh); h = z*h + (1-z)*ht
        k_gemm<FI, FI, HH, HH, 2><<<gH, 128, 0, stream>>>(
            xt, xbstride, pxt, hrbuf, ph,
            Wxh, Whh, bxh, bhh, nullptr, nullptr, nullptr, nullptr,
            hbuf, zbuf, hbuf, nullptr);
    }

    // out = relu(h) @ Wl + bl
    k_out<<<RB, 64, 0, stream>>>(hbuf, Wl, bl, out);
}

// Round 9
// 6581.368 us; speedup vs baseline: 1.2291x; 1.2291x over previous
//
#include <hip/hip_runtime.h>
#include <math.h>

#define NN 20000      // nodes
#define NE 320000     // edges
#define BB 2
#define TT 24
#define FI 32
#define HH 128

typedef __attribute__((ext_vector_type(4))) float f32x4;
typedef __attribute__((ext_vector_type(8))) short bf16x8;
typedef __attribute__((ext_vector_type(4))) short s16x4;

// ---------------- fp32 -> bf16 hi/lo split ----------------
__device__ __forceinline__ void split1(float f, short& hi, short& lo) {
    unsigned u = __float_as_uint(f);
    unsigned short h = (unsigned short)((u + 0x7FFFu + ((u >> 16) & 1u)) >> 16);
    float fh = __uint_as_float((unsigned)h << 16);
    float r = f - fh;
    unsigned v = __float_as_uint(r);
    unsigned short l = (unsigned short)((v + 0x7FFFu + ((v >> 16) & 1u)) >> 16);
    hi = (short)h; lo = (short)l;
}

// ---------------- edge_index dtype detection ----------------
// int64 (values < 2^31): every odd int32 word is a zero high-word.
__global__ void k_detect(const int* __restrict__ ei, int* __restrict__ flag) {
    int t = threadIdx.x;  // 64 threads
    int nz = 0;
    for (int i = 0; i < 4; ++i) nz |= (ei[2 * (t + 64 * i) + 1] != 0);
    unsigned long long m = __ballot(nz);
    if (t == 0) flag[0] = (m != 0ull) ? 0 : 1;   // 1 => int64
}

__device__ __forceinline__ int eidx(const int* __restrict__ ei, int i, int f64) {
    return f64 ? ei[2 * i] : ei[i];
}

// ---------------- graph preprocessing ----------------

__global__ void k_deg_count(const int* __restrict__ ei, const float* __restrict__ w,
                            float* __restrict__ deg, int* __restrict__ counts,
                            const int* __restrict__ flag) {
    int e = blockIdx.x * blockDim.x + threadIdx.x;
    if (e >= NE) return;
    int f64 = flag[0];
    int s = eidx(ei, e, f64);
    int d = eidx(ei, NE + e, f64);
    atomicAdd(&deg[s], w[e]);
    atomicAdd(&counts[d], 1);
}

__global__ void k_dinv(const float* __restrict__ deg, float* __restrict__ dinv) {
    int n = blockIdx.x * blockDim.x + threadIdx.x;
    if (n >= NN) return;
    float d = deg[n];
    dinv[n] = d > 0.f ? rsqrtf(d) : 0.f;
}

__global__ void k_norm(const int* __restrict__ ei, const float* __restrict__ w,
                       const float* __restrict__ dinv, float* __restrict__ normv,
                       const int* __restrict__ flag) {
    int e = blockIdx.x * blockDim.x + threadIdx.x;
    if (e >= NE) return;
    int f64 = flag[0];
    normv[e] = -dinv[eidx(ei, e, f64)] * w[e] * dinv[eidx(ei, NE + e, f64)];
}

// single-block exclusive scan of counts[NN] -> rowptr[NN+1]
__global__ void k_scan(const int* __restrict__ counts, int* __restrict__ rowptr) {
    __shared__ int sums[1024];
    int t = threadIdx.x;
    const int CH = (NN + 1023) / 1024;
    int start = t * CH;
    int s = 0;
    for (int i = 0; i < CH; ++i) {
        int idx = start + i;
        if (idx < NN) s += counts[idx];
    }
    sums[t] = s;
    __syncthreads();
    for (int off = 1; off < 1024; off *= 2) {
        int v = (t >= off) ? sums[t - off] : 0;
        __syncthreads();
        sums[t] += v;
        __syncthreads();
    }
    int run = (t > 0) ? sums[t - 1] : 0;
    for (int i = 0; i < CH; ++i) {
        int idx = start + i;
        if (idx < NN) { rowptr[idx] = run; run += counts[idx]; }
    }
    if (t == 1023) rowptr[NN] = sums[1023];
}

__global__ void k_copy_int(const int* __restrict__ src, int* __restrict__ dst, int n) {
    int i = blockIdx.x * blockDim.x + threadIdx.x;
    if (i < n) dst[i] = src[i];
}

__global__ void k_fill(const int* __restrict__ ei, const float* __restrict__ normv,
                       int* __restrict__ cursor, int* __restrict__ col, float* __restrict__ val,
                       const int* __restrict__ flag) {
    int e = blockIdx.x * blockDim.x + threadIdx.x;
    if (e >= NE) return;
    int f64 = flag[0];
    int d = eidx(ei, NE + e, f64);
    int p = atomicAdd(&cursor[d], 1);
    col[p] = eidx(ei, e, f64);
    val[p] = normv[e];
}

// ---------------- per-step SpMM + split (x side) ----------------
// block = node n, 64 threads (f = lane&31, b = lane>>5).
// writes px splits and x_t splits, both laid out [b*NN+n][32].
__global__ void k_prop_x_split(const float* __restrict__ x_seq, int t,
                               const int* __restrict__ rowptr, const int* __restrict__ col,
                               const float* __restrict__ val,
                               short* __restrict__ pxhi, short* __restrict__ pxlo,
                               short* __restrict__ xhi, short* __restrict__ xlo) {
    int n = blockIdx.x;
    int f = threadIdx.x & 31;
    int b = threadIdx.x >> 5;
    int beg = rowptr[n], end = rowptr[n + 1];
    const float* xb = x_seq + ((long)(b * TT + t) * NN) * FI;
    float acc = 0.f;
    for (int j = beg; j < end; ++j)
        acc += val[j] * xb[(long)col[j] * FI + f];
    long o = ((long)b * NN + n) * FI + f;
    short h, l;
    split1(acc, h, l);
    pxhi[o] = h; pxlo[o] = l;
    split1(xb[(long)n * FI + f], h, l);
    xhi[o] = h; xlo[o] = l;
}

// ---------------- SpMM + split (h side) ----------------
// 256 threads = 4 waves = 4 nodes; wave handles both batches:
// lanes 0-31 -> b=0, 32-63 -> b=1; lane covers 4 cols (float4).
__global__ void k_prop_h_split(const float* __restrict__ hin,
                               const int* __restrict__ rowptr, const int* __restrict__ col,
                               const float* __restrict__ val,
                               short* __restrict__ phi, short* __restrict__ plo) {
    int lane = threadIdx.x & 63;
    int n = blockIdx.x * 4 + (threadIdx.x >> 6);
    int b = lane >> 5;
    int c4 = (lane & 31) << 2;
    int beg = rowptr[n], end = rowptr[n + 1];
    const float* hb = hin + (long)b * NN * HH + c4;
    f32x4 acc = {0.f, 0.f, 0.f, 0.f};
    for (int j = beg; j < end; ++j) {
        float v = val[j];
        f32x4 q = *(const f32x4*)(hb + (long)col[j] * HH);
        acc += v * q;
    }
    long o = ((long)b * NN + n) * HH + c4;
    s16x4 hv, lv;
#pragma unroll
    for (int i = 0; i < 4; ++i) {
        short h, l;
        split1(acc[i], h, l);
        hv[i] = h; lv[i] = l;
    }
    *(s16x4*)(phi + o) = hv;
    *(s16x4*)(plo + o) = lv;
}

// ---------------- weight prep: combined [320][128] -> transposed bf16 hi/lo [128][320] ----
// combined row k: k<64 -> Wx[k][c] ([2][din][128] flat); else Wh[k-64][c].
__global__ void k_prep_w(const float* __restrict__ Wx, const float* __restrict__ Wh,
                         short* __restrict__ hi, short* __restrict__ lo) {
    int idx = blockIdx.x * blockDim.x + threadIdx.x;   // c*320 + k
    if (idx >= HH * 320) return;
    int c = idx / 320, k = idx - c * 320;
    float w = (k < 2 * FI) ? Wx[k * HH + c] : Wh[(k - 2 * FI) * HH + c];
    short h, l;
    split1(w, h, l);
    hi[idx] = h; lo[idx] = l;
}

// ---------------- MFMA split-bf16 quad-input GEMM ----------------
// v = [x | px | hA | phA] @ W + bx + bh   (K = 320, N = 128), all A pre-split bf16 hi/lo.
// x/px: [RB][32]; hA/phA: [RB][128]. W transposed split: Wt[c][k], k in [0,320).
// Block: 32 rows x 128 cols, 128 threads = 2 waves; wave w covers cols w*64.
// Wave tile: 2(m) x 4(n) fragments of 16x16; K-loop 10 steps of 32.
// 3-term split product: ah*wh + ah*wl + al*wh (al*wl ~2^-18 dropped).
// EPI 1: grid.y = gate. gate0: out0 = sigmoid(v) (z). gate1: hr = sigmoid(v)*hcur -> out1 + splits.
// EPI 2: ht = tanh(v); hnew = zin*hcur + (1-zin)*ht -> out0 + splits.
template<int EPI>
__global__ __launch_bounds__(128)
void k_gemm_mfma(const short* __restrict__ xhi, const short* __restrict__ xlo,
                 const short* __restrict__ pxhi, const short* __restrict__ pxlo,
                 const short* __restrict__ ahhi, const short* __restrict__ ahlo,
                 const short* __restrict__ aphi, const short* __restrict__ aplo,
                 const short* __restrict__ Whi0, const short* __restrict__ Wlo0,
                 const float* __restrict__ bx0, const float* __restrict__ bh0,
                 const short* __restrict__ Whi1, const short* __restrict__ Wlo1,
                 const float* __restrict__ bx1, const float* __restrict__ bh1,
                 const float* __restrict__ hcur,
                 const float* __restrict__ zin,
                 float* __restrict__ out0,
                 float* __restrict__ out1,
                 short* __restrict__ sohi,
                 short* __restrict__ solo) {
    const int tid = threadIdx.x;
    const int lane = tid & 63;
    const int wid = tid >> 6;        // 0..1
    const int lr = lane & 15;        // A row / W col / D col
    const int lg = lane >> 4;        // k-group (0..3)
    const int gate = (EPI == 1) ? (int)blockIdx.y : 0;
    const short* Whi = gate ? Whi1 : Whi0;
    const short* Wlo = gate ? Wlo1 : Wlo0;
    const float* bx  = gate ? bx1 : bx0;
    const float* bh  = gate ? bh1 : bh0;

    const int row_base = blockIdx.x * 32;
    const int col_base = wid * 64;

    long r32[2], r128[2];
#pragma unroll
    for (int m = 0; m < 2; ++m) {
        int row = row_base + m * 16 + lr;
        r32[m]  = (long)row * FI + lg * 8;
        r128[m] = (long)row * HH + lg * 8;
    }
    const long wbase = (long)(col_base + lr) * 320;

    f32x4 acc[2][4];
#pragma unroll
    for (int m = 0; m < 2; ++m)
#pragma unroll
        for (int n = 0; n < 4; ++n) acc[m][n] = (f32x4){0.f, 0.f, 0.f, 0.f};

#pragma unroll
    for (int ks = 0; ks < 10; ++ks) {
        bf16x8 ahi[2], alo[2];
#pragma unroll
        for (int m = 0; m < 2; ++m) {
            const short *ph_, *pl_;
            long off;
            if (ks == 0)      { ph_ = xhi;  pl_ = xlo;  off = r32[m]; }
            else if (ks == 1) { ph_ = pxhi; pl_ = pxlo; off = r32[m]; }
            else if (ks < 6)  { ph_ = ahhi; pl_ = ahlo; off = r128[m] + (ks - 2) * 32; }
            else              { ph_ = aphi; pl_ = aplo; off = r128[m] + (ks - 6) * 32; }
            ahi[m] = *(const bf16x8*)(ph_ + off);
            alo[m] = *(const bf16x8*)(pl_ + off);
        }
#pragma unroll
        for (int n = 0; n < 4; ++n) {
            const long wo = wbase + (long)n * (16 * 320) + ks * 32 + lg * 8;
            bf16x8 wh = *(const bf16x8*)(Whi + wo);
            bf16x8 wl = *(const bf16x8*)(Wlo + wo);
#pragma unroll
            for (int m = 0; m < 2; ++m) {
                acc[m][n] = __builtin_amdgcn_mfma_f32_16x16x32_bf16(ahi[m], wh, acc[m][n], 0, 0, 0);
                acc[m][n] = __builtin_amdgcn_mfma_f32_16x16x32_bf16(ahi[m], wl, acc[m][n], 0, 0, 0);
                acc[m][n] = __builtin_amdgcn_mfma_f32_16x16x32_bf16(alo[m], wh, acc[m][n], 0, 0, 0);
            }
        }
    }

    // epilogue: D col = lane&15, row = (lane>>4)*4 + reg  [m89/m91 verified]
#pragma unroll
    for (int m = 0; m < 2; ++m) {
#pragma unroll
        for (int n = 0; n < 4; ++n) {
            const int col = col_base + n * 16 + lr;
            const float bsum = bx[col] + bh[col];
#pragma unroll
            for (int j = 0; j < 4; ++j) {
                const int row = row_base + m * 16 + lg * 4 + j;
                const long o = (long)row * HH + col;
                float v = acc[m][n][j] + bsum;
                if (EPI == 1) {
                    float s = 1.f / (1.f + expf(-v));
                    if (gate == 0) {
                        out0[o] = s;                       // z
                    } else {
                        float hrv = s * hcur[o];           // h*r
                        out1[o] = hrv;
                        short hh, ll;
                        split1(hrv, hh, ll);
                        sohi[o] = hh; solo[o] = ll;
                    }
                } else {
                    float ht = tanhf(v);
                    float z = zin[o];
                    float hn = z * hcur[o] + (1.f - z) * ht;  // new h
                    out0[o] = hn;
                    short hh, ll;
                    split1(hn, hh, ll);
                    sohi[o] = hh; solo[o] = ll;
                }
            }
        }
    }
}

// ---------------- output head ----------------
__global__ void k_out(const float* __restrict__ h, const float* __restrict__ Wl,
                      const float* __restrict__ bl, float* __restrict__ out) {
    int row = blockIdx.x;        // 0 .. B*NN-1
    int lane = threadIdx.x;      // 64
    const float* hr = h + (long)row * HH;
    float a = fmaxf(hr[lane], 0.f) * Wl[lane] + fmaxf(hr[64 + lane], 0.f) * Wl[64 + lane];
#pragma unroll
    for (int off = 32; off > 0; off >>= 1) a += __shfl_down(a, off);
    if (lane == 0) out[row] = a + bl[0];
}

// ---------------- launcher ----------------
extern "C" void kernel_launch(void* const* d_in, const int* in_sizes, int n_in,
                              void* d_out, int out_size, void* d_ws, size_t ws_size,
                              hipStream_t stream) {
    const float* x_seq = (const float*)d_in[0];
    const int*   ei    = (const int*)d_in[1];
    const float* ew    = (const float*)d_in[2];
    const float* Wxz = (const float*)d_in[3],  *bxz = (const float*)d_in[4];
    const float* Whz = (const float*)d_in[5],  *bhz = (const float*)d_in[6];
    const float* Wxr = (const float*)d_in[7],  *bxr = (const float*)d_in[8];
    const float* Whr = (const float*)d_in[9],  *bhr = (const float*)d_in[10];
    const float* Wxh = (const float*)d_in[11], *bxh = (const float*)d_in[12];
    const float* Whh = (const float*)d_in[13], *bhh = (const float*)d_in[14];
    const float* Wl  = (const float*)d_in[15], *bl  = (const float*)d_in[16];
    float* out = (float*)d_out;

    char* p = (char*)d_ws;
    auto alloc = [&](size_t bytes) -> char* {
        char* r = p;
        p += (bytes + 255) & ~(size_t)255;
        return r;
    };
    const long RB = (long)BB * NN;  // 40000 rows

    int*   dflag  = (int*)alloc(4);
    float* deg    = (float*)alloc(NN * 4);
    float* dinv   = (float*)alloc(NN * 4);
    float* normv  = (float*)alloc(NE * 4);
    int*   counts = (int*)alloc(NN * 4);
    int*   rowptr = (int*)alloc((NN + 1) * 4);
    int*   cursor = (int*)alloc(NN * 4);
    int*   ccol   = (int*)alloc(NE * 4);
    float* cval   = (float*)alloc(NE * 4);
    float* hbuf   = (float*)alloc(RB * HH * 4);   // fp32 h (gather src, hcur, k_out)
    float* zbuf   = (float*)alloc(RB * HH * 4);   // fp32 z
    float* hrbuf  = (float*)alloc(RB * HH * 4);   // fp32 h*r (gather src)
    short* xthi   = (short*)alloc(RB * FI * 2);   // x_t split
    short* xtlo   = (short*)alloc(RB * FI * 2);
    short* pxhi   = (short*)alloc(RB * FI * 2);   // Ltilde@x_t split
    short* pxlo   = (short*)alloc(RB * FI * 2);
    short* hhi    = (short*)alloc(RB * HH * 2);   // h split
    short* hlo    = (short*)alloc(RB * HH * 2);
    short* hrhi   = (short*)alloc(RB * HH * 2);   // h*r split
    short* hrlo   = (short*)alloc(RB * HH * 2);
    short* phhi   = (short*)alloc(RB * HH * 2);   // Ltilde@h / Ltilde@(h*r) split
    short* phlo   = (short*)alloc(RB * HH * 2);
    short* WtZhi  = (short*)alloc(HH * 320 * 2);
    short* WtZlo  = (short*)alloc(HH * 320 * 2);
    short* WtRhi  = (short*)alloc(HH * 320 * 2);
    short* WtRlo  = (short*)alloc(HH * 320 * 2);
    short* WtHhi  = (short*)alloc(HH * 320 * 2);
    short* WtHlo  = (short*)alloc(HH * 320 * 2);

    // graph preprocessing
    hipMemsetAsync(deg, 0, NN * 4, stream);
    hipMemsetAsync(counts, 0, NN * 4, stream);
    k_detect<<<1, 64, 0, stream>>>(ei, dflag);
    k_deg_count<<<(NE + 255) / 256, 256, 0, stream>>>(ei, ew, deg, counts, dflag);
    k_dinv<<<(NN + 255) / 256, 256, 0, stream>>>(deg, dinv);
    k_norm<<<(NE + 255) / 256, 256, 0, stream>>>(ei, ew, dinv, normv, dflag);
    k_scan<<<1, 1024, 0, stream>>>(counts, rowptr);
    k_copy_int<<<(NN + 255) / 256, 256, 0, stream>>>(rowptr, cursor, NN);
    k_fill<<<(NE + 255) / 256, 256, 0, stream>>>(ei, normv, cursor, ccol, cval, dflag);

    // weight prep (transposed bf16 hi/lo)
    const int WPE = HH * 320;
    k_prep_w<<<(WPE + 255) / 256, 256, 0, stream>>>(Wxz, Whz, WtZhi, WtZlo);
    k_prep_w<<<(WPE + 255) / 256, 256, 0, stream>>>(Wxr, Whr, WtRhi, WtRlo);
    k_prep_w<<<(WPE + 255) / 256, 256, 0, stream>>>(Wxh, Whh, WtHhi, WtHlo);

    // h0 = 0 (fp32 and splits)
    hipMemsetAsync(hbuf, 0, RB * HH * 4, stream);
    hipMemsetAsync(hhi, 0, RB * HH * 2, stream);
    hipMemsetAsync(hlo, 0, RB * HH * 2, stream);

    dim3 gZR(1250, 2), gH(1250, 1);
    for (int t = 0; t < TT; ++t) {
        // x-side SpMM + x_t/px split (per-step: 5 MB working set, cache-hot)
        k_prop_x_split<<<NN, 64, 0, stream>>>(x_seq, t, rowptr, ccol, cval,
                                              pxhi, pxlo, xthi, xtlo);
        // ph = Ltilde @ h (split output)
        k_prop_h_split<<<NN / 4, 256, 0, stream>>>(hbuf, rowptr, ccol, cval, phhi, phlo);
        // z = sigmoid([x|px|h|ph]@Wz+b) (gate 0 -> zbuf); hr = sigmoid(...Wr...)*h (gate 1 -> hrbuf+splits)
        k_gemm_mfma<1><<<gZR, 128, 0, stream>>>(
            xthi, xtlo, pxhi, pxlo, hhi, hlo, phhi, phlo,
            WtZhi, WtZlo, bxz, bhz, WtRhi, WtRlo, bxr, bhr,
            hbuf, nullptr, zbuf, hrbuf, hrhi, hrlo);
        // phr = Ltilde @ (h*r)
        k_prop_h_split<<<NN / 4, 256, 0, stream>>>(hrbuf, rowptr, ccol, cval, phhi, phlo);
        // ht = tanh([x|px|hr|phr]@Wh+b); h = z*h + (1-z)*ht  (-> hbuf + splits)
        k_gemm_mfma<2><<<gH, 128, 0, stream>>>(
            xthi, xtlo, pxhi, pxlo, hrhi, hrlo, phhi, phlo,
            WtHhi, WtHlo, bxh, bhh, nullptr, nullptr, nullptr, nullptr,
            hbuf, zbuf, hbuf, nullptr, hhi, hlo);
    }

    // out = relu(h) @ Wl + bl
    k_out<<<RB, 64, 0, stream>>>(hbuf, Wl, bl, out);
}